// Round 8
// baseline (120.400 us; speedup 1.0000x reference)
//
#include <hip/hip_runtime.h>
#include <stdint.h>

// Problem constants (fixed by the reference)
#define NB    32768   // batch
#define NS    16      // states per element
#define SS    32      // state size (K of stage 1)
#define ENCD  64      // encoder width
#define HIDD  128     // hidden width
#define OUTD  8       // output logits
#define BT    32      // batch elements per block (r8: doubled from 16)
#define BPW   8       // batches per wave in stage 1
#define THREADS 256   // 4 waves

typedef _Float16 half8  __attribute__((ext_vector_type(8)));  // 8 f16 = 4 VGPRs
typedef __fp16   fp16x2 __attribute__((ext_vector_type(2)));  // cvt_pkrtz result type
typedef float    f32x4  __attribute__((ext_vector_type(4)));

#define MFMA(a, b, c) __builtin_amdgcn_mfma_f32_16x16x32_f16((a), (b), (c), 0, 0, 0)

// Split 8 floats into fp16 hi + lo: f = hi + lo + O(2^-20 |f|).
__device__ __forceinline__ void split8(const float* f, half8& hi, half8& lo) {
#pragma unroll
  for (int j = 0; j < 8; j += 2) {
    fp16x2 h  = __builtin_amdgcn_cvt_pkrtz(f[j], f[j + 1]);
    float  r0 = f[j]     - (float)h[0];
    float  r1 = f[j + 1] - (float)h[1];
    fp16x2 l2 = __builtin_amdgcn_cvt_pkrtz(r0, r1);
    hi[j] = (_Float16)(float)h[0];  hi[j + 1] = (_Float16)(float)h[1];
    lo[j] = (_Float16)(float)l2[0]; lo[j + 1] = (_Float16)(float)l2[1];
  }
}

// R7 post-mortem: stage-3 depth-1 prefetch = new best (111.7). Remaining cost
// scales with BLOCK COUNT: W_f L2 traffic (64KB/block) + weight split8 VALU
// (~60% of VALU ops). R8, one coherent change: BT 16->32. Stage 3 runs TWO
// 16-row M-tiles off ONE W_f fragment stream (loads+splits per batch halve);
// stage 4 uses waves 0+1 (one tile each); grid 1024 = exactly 4 blocks/CU
// co-resident under (256,4). Spill tripwire: WRITE_SIZE must stay ~1 MB.
__global__ __launch_bounds__(THREADS, 4)
void gnn_fused(const float* __restrict__ obs,
               const float* __restrict__ W_enc,
               const float* __restrict__ b_enc,
               const float* __restrict__ W_f,
               const float* __restrict__ b_f,
               const float* __restrict__ W_dec,
               const float* __restrict__ b_dec,
               float* __restrict__ out)
{
  // stride 132 floats: rows 528 B (16B-aligned), row-to-row bank shift of 4
  __shared__ __align__(16) float f_in[BT][132];   // stage-2 output [batch][128]
  __shared__ __align__(16) float hidn[BT][132];   // stage-3 output [batch][128]

  const int tid  = threadIdx.x;
  const int w    = tid >> 6;     // wave 0..3
  const int l    = tid & 63;     // lane
  const int m15  = l & 15;
  const int quad = l >> 4;
  const int b0   = blockIdx.x * BT;

  // ---- stage-1 B-fragments: W_enc[k][e] columns, hi/lo fp16, in regs (32 VGPRs)
  half8 we_hi[4], we_lo[4];
  float benc[4];
#pragma unroll
  for (int nt = 0; nt < 4; ++nt) {
    float f[8];
#pragma unroll
    for (int j = 0; j < 8; ++j)
      f[j] = W_enc[(size_t)(quad * 8 + j) * ENCD + nt * 16 + m15];
    split8(f, we_hi[nt], we_lo[nt]);
    benc[nt] = b_enc[nt * 16 + m15];
  }

  // ================= stage 1 (enc MFMA) + stage 2 (masked mean-pool) =========
  // wave handles batches [b0 + w*8, b0 + w*8 + 8), depth-1 rotating prefetch
  const float* bp = obs + (size_t)(b0 + w * BPW) * (NS * SS) + m15 * SS + quad * 8;
  float4 c0 = ((const float4*)bp)[0];
  float4 c1 = ((const float4*)bp)[1];
#pragma unroll
  for (int i = 0; i < BPW; ++i) {
    float4 n0, n1;
    if (i < BPW - 1) {  // prefetch next batch element
      const float* np = bp + (size_t)(i + 1) * (NS * SS);
      n0 = ((const float4*)np)[0];
      n1 = ((const float4*)np)[1];
    } else { n0 = c0; n1 = c1; }

    float f[8] = {c0.x, c0.y, c0.z, c0.w, c1.x, c1.y, c1.z, c1.w};

    // flags: lanes 0..15 hold states[b][n][0]; cumprod run length via ballot+ctz
    unsigned long long bal = __ballot((l < 16) && (f[0] == 1.0f));
    int run = __builtin_ctzll(~(bal >> 1));      // consecutive valid neighbors
    float inv = 1.0f / fmaxf((float)run, 1.0f);

    half8 ahi, alo;
    split8(f, ahi, alo);

    const int bi = w * BPW + i;  // local batch row, 0..31
#pragma unroll
    for (int nt = 0; nt < 4; ++nt) {
      f32x4 acc = {0.f, 0.f, 0.f, 0.f};
      acc = MFMA(ahi, we_hi[nt], acc);
      acc = MFMA(alo, we_hi[nt], acc);
      acc = MFMA(ahi, we_lo[nt], acc);
      // D layout: lane holds enc[n = quad*4 + r][e = nt*16 + m15]
      float s = 0.f, e0 = 0.f;
#pragma unroll
      for (int r = 0; r < 4; ++r) {
        int n = quad * 4 + r;
        float v = fmaxf(acc[r] + benc[nt], 0.f);
        if (n == 0) e0 = v;                    // agent row
        if (n >= 1 && n <= run) s += v;        // valid neighbor
      }
      s += __shfl_xor(s, 16, 64);              // reduce across quads
      s += __shfl_xor(s, 32, 64);
      if (quad == 0) {
        f_in[bi][nt * 16 + m15]      = e0;      // agent_enc
        f_in[bi][64 + nt * 16 + m15] = s * inv; // agg
      }
    }
    c0 = n0; c1 = n1;
  }
  __syncthreads();

  // ================= stage 3: hidden = relu(f_in @ W_f + b_f) ================
  // TWO 16-row M-tiles (rows 0-15, 16-31); wave w covers N-tiles 2w, 2w+1.
  // One W_f fragment stream (depth-1 prefetched, r7) feeds BOTH tiles:
  // per-batch weight load + split cost is halved vs BT=16.
  {
    half8 fa0_hi[4], fa0_lo[4], fa1_hi[4], fa1_lo[4];
#pragma unroll
    for (int ks = 0; ks < 4; ++ks) {
      const float4* p0 = (const float4*)&f_in[m15][ks * 32 + quad * 8];
      float4 a = p0[0], b = p0[1];
      float f[8] = {a.x, a.y, a.z, a.w, b.x, b.y, b.z, b.w};
      split8(f, fa0_hi[ks], fa0_lo[ks]);
      const float4* p1 = (const float4*)&f_in[16 + m15][ks * 32 + quad * 8];
      float4 c = p1[0], d = p1[1];
      float g[8] = {c.x, c.y, c.z, c.w, d.x, d.y, d.z, d.w};
      split8(g, fa1_hi[ks], fa1_lo[ks]);
    }
    const float bf0 = b_f[(w * 2) * 16 + m15];       // hoisted off the tail
    const float bf1 = b_f[(w * 2 + 1) * 16 + m15];

    float cur[8], nxt[8];
#pragma unroll
    for (int j = 0; j < 8; ++j)                      // s=0 fragment (tt=0,ks=0)
      cur[j] = W_f[(size_t)(quad * 8 + j) * HIDD + (w * 2) * 16 + m15];

    f32x4 acc0 = {0.f, 0.f, 0.f, 0.f};
    f32x4 acc1 = {0.f, 0.f, 0.f, 0.f};
#pragma unroll
    for (int s = 0; s < 8; ++s) {
      const int tt = s >> 2, ks = s & 3;
      if (s < 7) {                                   // prefetch step s+1
        const int nt2 = (s + 1) >> 2, nk = (s + 1) & 3;
        const int hn  = (w * 2 + nt2) * 16 + m15;
#pragma unroll
        for (int j = 0; j < 8; ++j)
          nxt[j] = W_f[(size_t)(nk * 32 + quad * 8 + j) * HIDD + hn];
      }
      half8 bhi, blo;
      split8(cur, bhi, blo);                          // ONE split, TWO tiles
      acc0 = MFMA(fa0_hi[ks], bhi, acc0);
      acc0 = MFMA(fa0_lo[ks], bhi, acc0);
      acc0 = MFMA(fa0_hi[ks], blo, acc0);
      acc1 = MFMA(fa1_hi[ks], bhi, acc1);
      acc1 = MFMA(fa1_lo[ks], bhi, acc1);
      acc1 = MFMA(fa1_hi[ks], blo, acc1);
      if (ks == 3) {
        const int   hc  = (w * 2 + tt) * 16 + m15;
        const float bfv = tt ? bf1 : bf0;
#pragma unroll
        for (int r = 0; r < 4; ++r) {                // D: row = batch, col = hc
          hidn[quad * 4 + r][hc]      = fmaxf(acc0[r] + bfv, 0.f);
          hidn[16 + quad * 4 + r][hc] = fmaxf(acc1[r] + bfv, 0.f);
        }
        acc0 = (f32x4){0.f, 0.f, 0.f, 0.f};
        acc1 = (f32x4){0.f, 0.f, 0.f, 0.f};
      }
#pragma unroll
      for (int j = 0; j < 8; ++j) cur[j] = nxt[j];   // rotate (SSA-renamed)
    }
  }
  __syncthreads();

  // ================= stage 4: logits = hidden @ W_dec + b_dec ================
  // waves 0 and 1, one 16-row M-tile each (rows w*16 .. w*16+15)
  if (w < 2) {
    half8 ga_hi[4], ga_lo[4];
#pragma unroll
    for (int ks = 0; ks < 4; ++ks) {
      const float4* p = (const float4*)&hidn[w * 16 + m15][ks * 32 + quad * 8];
      float4 a = p[0], b = p[1];
      float f[8] = {a.x, a.y, a.z, a.w, b.x, b.y, b.z, b.w};
      split8(f, ga_hi[ks], ga_lo[ks]);
    }
    f32x4 acc = {0.f, 0.f, 0.f, 0.f};
#pragma unroll
    for (int ks = 0; ks < 4; ++ks) {
      float f[8];
#pragma unroll
      for (int j = 0; j < 8; ++j) {
        int k = ks * 32 + quad * 8 + j;
        f[j] = (m15 < OUTD) ? W_dec[(size_t)k * OUTD + m15] : 0.f;  // pad N 8->16
      }
      half8 bhi, blo;
      split8(f, bhi, blo);
      acc = MFMA(ga_hi[ks], bhi, acc);
      acc = MFMA(ga_lo[ks], bhi, acc);
      acc = MFMA(ga_hi[ks], blo, acc);
    }
    if (m15 < OUTD) {
      const float bd = b_dec[m15];
#pragma unroll
      for (int r = 0; r < 4; ++r) {
        const int m = w * 16 + quad * 4 + r;         // block-local batch row
        out[(size_t)(b0 + m) * OUTD + m15] = acc[r] + bd;
      }
    }
  }
}

extern "C" void kernel_launch(void* const* d_in, const int* in_sizes, int n_in,
                              void* d_out, int out_size, void* d_ws, size_t ws_size,
                              hipStream_t stream) {
  (void)in_sizes; (void)n_in; (void)d_ws; (void)ws_size; (void)out_size;
  const float* obs   = (const float*)d_in[0];
  const float* W_enc = (const float*)d_in[1];
  const float* b_enc = (const float*)d_in[2];
  const float* W_f   = (const float*)d_in[3];
  const float* b_f   = (const float*)d_in[4];
  const float* W_dec = (const float*)d_in[5];
  const float* b_dec = (const float*)d_in[6];
  float* out = (float*)d_out;

  dim3 grid(NB / BT);      // 1024 blocks = exactly 4/CU co-resident
  dim3 block(THREADS);     // 256 threads = 4 waves
  gnn_fused<<<grid, block, 0, stream>>>(obs, W_enc, b_enc, W_f, b_f, W_dec, b_dec, out);
}

// Round 9
// 114.601 us; speedup vs baseline: 1.0506x; 1.0506x over previous
//
#include <hip/hip_runtime.h>
#include <stdint.h>

// Problem constants (fixed by the reference)
#define NB    32768   // batch
#define NS    16      // states per element
#define SS    32      // state size (K of stage 1)
#define ENCD  64      // encoder width
#define HIDD  128     // hidden width
#define OUTD  8       // output logits
#define BT    16      // batch elements per block
#define THREADS 256   // 4 waves

typedef _Float16 half8  __attribute__((ext_vector_type(8)));  // 8 f16 = 4 VGPRs
typedef __fp16   fp16x2 __attribute__((ext_vector_type(2)));  // cvt_pkrtz result type
typedef float    f32x4  __attribute__((ext_vector_type(4)));

#define MFMA(a, b, c) __builtin_amdgcn_mfma_f32_16x16x32_f16((a), (b), (c), 0, 0, 0)

// Split 8 floats into fp16 hi + lo: f = hi + lo + O(2^-20 |f|).
__device__ __forceinline__ void split8(const float* f, half8& hi, half8& lo) {
#pragma unroll
  for (int j = 0; j < 8; j += 2) {
    fp16x2 h  = __builtin_amdgcn_cvt_pkrtz(f[j], f[j + 1]);
    float  r0 = f[j]     - (float)h[0];
    float  r1 = f[j + 1] - (float)h[1];
    fp16x2 l2 = __builtin_amdgcn_cvt_pkrtz(r0, r1);
    hi[j] = (_Float16)(float)h[0];  hi[j + 1] = (_Float16)(float)h[1];
    lo[j] = (_Float16)(float)l2[0]; lo[j + 1] = (_Float16)(float)l2[1];
  }
}

// R8 post-mortem: BT=32 (halved weight traffic) REGRESSED +8.7us -> weight
// redundancy is hidden; stage-1's serial per-wave obs chain is the stall.
// R3 retro-explained: it issued obs BEFORE W_enc; vmcnt FIFO forced the
// prologue's W_enc wait to drain the older HBM obs loads (~900cy) first.
// R9 = r7 with ONE change: full-depth obs staging issued AFTER W_enc/b_enc,
// one sched_barrier(0) after the whole load group. FIFO now helps: splits
// wait vmcnt(8) (W_enc only); batch i consumes at vmcnt(6/4/2/0) — obs
// latency hides under prologue splits + earlier iterations.
__global__ __launch_bounds__(THREADS, 4)
void gnn_fused(const float* __restrict__ obs,
               const float* __restrict__ W_enc,
               const float* __restrict__ b_enc,
               const float* __restrict__ W_f,
               const float* __restrict__ b_f,
               const float* __restrict__ W_dec,
               const float* __restrict__ b_dec,
               float* __restrict__ out)
{
  // stride 132 floats: rows 528 B (16B-aligned), row-to-row bank shift of 4
  __shared__ __align__(16) float f_in[BT][132];   // stage-2 output [batch][128]
  __shared__ __align__(16) float hidn[BT][132];   // stage-3 output [batch][128]

  const int tid  = threadIdx.x;
  const int w    = tid >> 6;     // wave 0..3
  const int l    = tid & 63;     // lane
  const int m15  = l & 15;
  const int quad = l >> 4;
  const int b0   = blockIdx.x * BT;

  // ---- LOAD GROUP, in FIFO-friendly order ------------------------------
  // (1) W_enc columns (L2, needed first by the prologue splits)
  float wef[4][8];
#pragma unroll
  for (int nt = 0; nt < 4; ++nt)
#pragma unroll
    for (int j = 0; j < 8; ++j)
      wef[nt][j] = W_enc[(size_t)(quad * 8 + j) * ENCD + nt * 16 + m15];
  // (2) b_enc (L2)
  float benc[4];
#pragma unroll
  for (int nt = 0; nt < 4; ++nt)
    benc[nt] = b_enc[nt * 16 + m15];
  // (3) obs, ALL 4 batch elements for this wave (HBM, needed later):
  //     8 x dwordx4 in flight behind the W_enc loads.
  const float* bp = obs + (size_t)(b0 + w * 4) * (NS * SS) + m15 * SS + quad * 8;
  float4 A0[4], A1[4];
#pragma unroll
  for (int i = 0; i < 4; ++i) {
    const float4* p = (const float4*)(bp + (size_t)i * (NS * SS));
    A0[i] = p[0]; A1[i] = p[1];
  }
  __builtin_amdgcn_sched_barrier(0);   // pin the group: nothing sinks below

  // ---- stage-1 B-fragments: split W_enc (waits vmcnt(8): W_enc only)
  half8 we_hi[4], we_lo[4];
#pragma unroll
  for (int nt = 0; nt < 4; ++nt)
    split8(wef[nt], we_hi[nt], we_lo[nt]);

  // ================= stage 1 (enc MFMA) + stage 2 (masked mean-pool) =========
  // wave handles batches [b0 + w*4, b0 + w*4 + 4); slot i consumed at
  // vmcnt(6/4/2/0) — no refill logic, all loads already in flight.
#pragma unroll
  for (int i = 0; i < 4; ++i) {
    float f[8] = {A0[i].x, A0[i].y, A0[i].z, A0[i].w,
                  A1[i].x, A1[i].y, A1[i].z, A1[i].w};

    // flags: lanes 0..15 hold states[b][n][0]; cumprod run length via ballot+ctz
    unsigned long long bal = __ballot((l < 16) && (f[0] == 1.0f));
    int run = __builtin_ctzll(~(bal >> 1));      // consecutive valid neighbors
    float inv = 1.0f / fmaxf((float)run, 1.0f);

    half8 ahi, alo;
    split8(f, ahi, alo);

    const int bi = w * 4 + i;  // local batch row
#pragma unroll
    for (int nt = 0; nt < 4; ++nt) {
      f32x4 acc = {0.f, 0.f, 0.f, 0.f};
      acc = MFMA(ahi, we_hi[nt], acc);
      acc = MFMA(alo, we_hi[nt], acc);
      acc = MFMA(ahi, we_lo[nt], acc);
      // D layout: lane holds enc[n = quad*4 + r][e = nt*16 + m15]
      float s = 0.f, e0 = 0.f;
#pragma unroll
      for (int r = 0; r < 4; ++r) {
        int n = quad * 4 + r;
        float v = fmaxf(acc[r] + benc[nt], 0.f);
        if (n == 0) e0 = v;                    // agent row
        if (n >= 1 && n <= run) s += v;        // valid neighbor
      }
      s += __shfl_xor(s, 16, 64);              // reduce across quads
      s += __shfl_xor(s, 32, 64);
      if (quad == 0) {
        f_in[bi][nt * 16 + m15]      = e0;      // agent_enc
        f_in[bi][64 + nt * 16 + m15] = s * inv; // agg
      }
    }
  }
  __syncthreads();

  // ================= stage 3: hidden = relu(f_in @ W_f + b_f) ================
  // single 16-row M-tile; wave w covers N-tiles 2w, 2w+1. Flat s = tt*4+ks loop
  // with depth-1 W_f prefetch (r7: kept, -1.8us).
  {
    half8 fa_hi[4], fa_lo[4];
#pragma unroll
    for (int ks = 0; ks < 4; ++ks) {
      const float4* p = (const float4*)&f_in[m15][ks * 32 + quad * 8];
      float4 a = p[0], b = p[1];
      float f[8] = {a.x, a.y, a.z, a.w, b.x, b.y, b.z, b.w};
      split8(f, fa_hi[ks], fa_lo[ks]);
    }
    const float bf0 = b_f[(w * 2) * 16 + m15];       // hoisted off the tail
    const float bf1 = b_f[(w * 2 + 1) * 16 + m15];

    float cur[8], nxt[8];
#pragma unroll
    for (int j = 0; j < 8; ++j)                      // s=0 fragment (tt=0,ks=0)
      cur[j] = W_f[(size_t)(quad * 8 + j) * HIDD + (w * 2) * 16 + m15];

    f32x4 acc = {0.f, 0.f, 0.f, 0.f};
#pragma unroll
    for (int s = 0; s < 8; ++s) {
      const int tt = s >> 2, ks = s & 3;
      if (s < 7) {                                   // prefetch step s+1
        const int nt2 = (s + 1) >> 2, nk = (s + 1) & 3;
        const int hn  = (w * 2 + nt2) * 16 + m15;
#pragma unroll
        for (int j = 0; j < 8; ++j)
          nxt[j] = W_f[(size_t)(nk * 32 + quad * 8 + j) * HIDD + hn];
      }
      half8 bhi, blo;
      split8(cur, bhi, blo);
      acc = MFMA(fa_hi[ks], bhi, acc);
      acc = MFMA(fa_lo[ks], bhi, acc);
      acc = MFMA(fa_hi[ks], blo, acc);
      if (ks == 3) {
        const int   hc  = (w * 2 + tt) * 16 + m15;
        const float bfv = tt ? bf1 : bf0;
#pragma unroll
        for (int r = 0; r < 4; ++r)                  // D: row = batch, col = hc
          hidn[quad * 4 + r][hc] = fmaxf(acc[r] + bfv, 0.f);
        acc = (f32x4){0.f, 0.f, 0.f, 0.f};
      }
#pragma unroll
      for (int j = 0; j < 8; ++j) cur[j] = nxt[j];   // rotate (SSA-renamed)
    }
  }
  __syncthreads();

  // ================= stage 4: logits = hidden @ W_dec + b_dec ================
  if (w == 0) {                                  // one 16-row M-tile (r0 form)
    half8 ga_hi[4], ga_lo[4];
#pragma unroll
    for (int ks = 0; ks < 4; ++ks) {
      const float4* p = (const float4*)&hidn[m15][ks * 32 + quad * 8];
      float4 a = p[0], b = p[1];
      float f[8] = {a.x, a.y, a.z, a.w, b.x, b.y, b.z, b.w};
      split8(f, ga_hi[ks], ga_lo[ks]);
    }
    f32x4 acc = {0.f, 0.f, 0.f, 0.f};
#pragma unroll
    for (int ks = 0; ks < 4; ++ks) {
      float f[8];
#pragma unroll
      for (int j = 0; j < 8; ++j) {
        int k = ks * 32 + quad * 8 + j;
        f[j] = (m15 < OUTD) ? W_dec[(size_t)k * OUTD + m15] : 0.f;  // pad N 8->16
      }
      half8 bhi, blo;
      split8(f, bhi, blo);
      acc = MFMA(ga_hi[ks], bhi, acc);
      acc = MFMA(ga_lo[ks], bhi, acc);
      acc = MFMA(ga_hi[ks], blo, acc);
    }
    if (m15 < OUTD) {
      const float bd = b_dec[m15];
#pragma unroll
      for (int r = 0; r < 4; ++r) {
        const int m = quad * 4 + r;
        out[(size_t)(b0 + m) * OUTD + m15] = acc[r] + bd;
      }
    }
  }
}

extern "C" void kernel_launch(void* const* d_in, const int* in_sizes, int n_in,
                              void* d_out, int out_size, void* d_ws, size_t ws_size,
                              hipStream_t stream) {
  (void)in_sizes; (void)n_in; (void)d_ws; (void)ws_size; (void)out_size;
  const float* obs   = (const float*)d_in[0];
  const float* W_enc = (const float*)d_in[1];
  const float* b_enc = (const float*)d_in[2];
  const float* W_f   = (const float*)d_in[3];
  const float* b_f   = (const float*)d_in[4];
  const float* W_dec = (const float*)d_in[5];
  const float* b_dec = (const float*)d_in[6];
  float* out = (float*)d_out;

  dim3 grid(NB / BT);      // 2048 blocks
  dim3 block(THREADS);     // 256 threads = 4 waves
  gnn_fused<<<grid, block, 0, stream>>>(obs, W_enc, b_enc, W_f, b_f, W_dec, b_dec, out);
}

// Round 10
// 111.173 us; speedup vs baseline: 1.0830x; 1.0308x over previous
//
#include <hip/hip_runtime.h>
#include <stdint.h>

// Problem constants (fixed by the reference)
#define NB    32768   // batch
#define NS    16      // states per element
#define SS    32      // state size (K of stage 1)
#define ENCD  64      // encoder width
#define HIDD  128     // hidden width
#define OUTD  8       // output logits
#define BT    16      // batch elements per block
#define THREADS 256   // 4 waves

typedef _Float16 half8  __attribute__((ext_vector_type(8)));  // 8 f16 = 4 VGPRs
typedef __fp16   fp16x2 __attribute__((ext_vector_type(2)));  // cvt_pkrtz result type
typedef float    f32x4  __attribute__((ext_vector_type(4)));

#define MFMA(a, b, c) __builtin_amdgcn_mfma_f32_16x16x32_f16((a), (b), (c), 0, 0, 0)

// Split 8 floats into fp16 hi + lo: f = hi + lo + O(2^-20 |f|).
// Used for ACTIVATIONS (A-side) and the final layer only.
__device__ __forceinline__ void split8(const float* f, half8& hi, half8& lo) {
#pragma unroll
  for (int j = 0; j < 8; j += 2) {
    fp16x2 h  = __builtin_amdgcn_cvt_pkrtz(f[j], f[j + 1]);
    float  r0 = f[j]     - (float)h[0];
    float  r1 = f[j + 1] - (float)h[1];
    fp16x2 l2 = __builtin_amdgcn_cvt_pkrtz(r0, r1);
    hi[j] = (_Float16)(float)h[0];  hi[j + 1] = (_Float16)(float)h[1];
    lo[j] = (_Float16)(float)l2[0]; lo[j + 1] = (_Float16)(float)l2[1];
  }
}

// R10: hi-ONLY weight conversion (RTN casts, rel err 2^-12). Replaces 28-op
// split8 with ~8-10 ops; drops the B-lo MFMA (3 -> 2 per fragment pair).
__device__ __forceinline__ void cvt8(const float* f, half8& hi) {
#pragma unroll
  for (int j = 0; j < 8; ++j)
    hi[j] = (_Float16)f[j];     // RTN: max rel err 2^-12 (vs RTZ 2^-11)
}

// R9 post-mortem: sched_barrier variants (r3, r9) ALWAYS regress — compiler
// schedule + wave overlap wins. Schedule tweaks are noise-floored; only
// instruction VOLUME is left. R10 = r7 base, weights hi-only in stages 1+3:
// -270 VALU ops and -24 MFMA per thread, identical memory pattern, zero new
// sync. Stage 4 keeps full hi+lo precision (feeds absmax directly). Expected
// absmax 4.9e-4 -> ~6-8e-4 (error budget: +~1e-4/layer, attenuated by 0.05-
// scale weights downstream).
__global__ __launch_bounds__(THREADS, 4)
void gnn_fused(const float* __restrict__ obs,
               const float* __restrict__ W_enc,
               const float* __restrict__ b_enc,
               const float* __restrict__ W_f,
               const float* __restrict__ b_f,
               const float* __restrict__ W_dec,
               const float* __restrict__ b_dec,
               float* __restrict__ out)
{
  // stride 132 floats: rows 528 B (16B-aligned), row-to-row bank shift of 4
  __shared__ __align__(16) float f_in[BT][132];   // stage-2 output [batch][128]
  __shared__ __align__(16) float hidn[BT][132];   // stage-3 output [batch][128]

  const int tid  = threadIdx.x;
  const int w    = tid >> 6;     // wave 0..3
  const int l    = tid & 63;     // lane
  const int m15  = l & 15;
  const int quad = l >> 4;
  const int b0   = blockIdx.x * BT;

  // ---- stage-1 B-fragments: W_enc[k][e] columns, hi-only fp16 (16 VGPRs)
  half8 we_hi[4];
  float benc[4];
#pragma unroll
  for (int nt = 0; nt < 4; ++nt) {
    float f[8];
#pragma unroll
    for (int j = 0; j < 8; ++j)
      f[j] = W_enc[(size_t)(quad * 8 + j) * ENCD + nt * 16 + m15];
    cvt8(f, we_hi[nt]);
    benc[nt] = b_enc[nt * 16 + m15];
  }

  // ================= stage 1 (enc MFMA) + stage 2 (masked mean-pool) =========
  // wave handles batches [b0 + w*4, b0 + w*4 + 4), depth-1 rotating prefetch
  const float* bp = obs + (size_t)(b0 + w * 4) * (NS * SS) + m15 * SS + quad * 8;
  float4 c0 = ((const float4*)bp)[0];
  float4 c1 = ((const float4*)bp)[1];
#pragma unroll
  for (int i = 0; i < 4; ++i) {
    float4 n0, n1;
    if (i < 3) {  // prefetch next batch element
      const float* np = bp + (size_t)(i + 1) * (NS * SS);
      n0 = ((const float4*)np)[0];
      n1 = ((const float4*)np)[1];
    } else { n0 = c0; n1 = c1; }

    float f[8] = {c0.x, c0.y, c0.z, c0.w, c1.x, c1.y, c1.z, c1.w};

    // flags: lanes 0..15 hold states[b][n][0]; cumprod run length via ballot+ctz
    unsigned long long bal = __ballot((l < 16) && (f[0] == 1.0f));
    int run = __builtin_ctzll(~(bal >> 1));      // consecutive valid neighbors
    float inv = 1.0f / fmaxf((float)run, 1.0f);

    half8 ahi, alo;
    split8(f, ahi, alo);                         // A keeps hi+lo (exact-ish)

    const int bi = w * 4 + i;  // local batch row
#pragma unroll
    for (int nt = 0; nt < 4; ++nt) {
      f32x4 acc = {0.f, 0.f, 0.f, 0.f};
      acc = MFMA(ahi, we_hi[nt], acc);           // 2 MFMAs (B-lo dropped)
      acc = MFMA(alo, we_hi[nt], acc);
      // D layout: lane holds enc[n = quad*4 + r][e = nt*16 + m15]
      float s = 0.f, e0 = 0.f;
#pragma unroll
      for (int r = 0; r < 4; ++r) {
        int n = quad * 4 + r;
        float v = fmaxf(acc[r] + benc[nt], 0.f);
        if (n == 0) e0 = v;                    // agent row
        if (n >= 1 && n <= run) s += v;        // valid neighbor
      }
      s += __shfl_xor(s, 16, 64);              // reduce across quads
      s += __shfl_xor(s, 32, 64);
      if (quad == 0) {
        f_in[bi][nt * 16 + m15]      = e0;      // agent_enc
        f_in[bi][64 + nt * 16 + m15] = s * inv; // agg
      }
    }
    c0 = n0; c1 = n1;
  }
  __syncthreads();

  // ================= stage 3: hidden = relu(f_in @ W_f + b_f) ================
  // single 16-row M-tile; wave w covers N-tiles 2w, 2w+1. Flat s = tt*4+ks loop
  // with depth-1 W_f prefetch (r7). Weights hi-only: cvt8 + 2 MFMAs per step.
  {
    half8 fa_hi[4], fa_lo[4];
#pragma unroll
    for (int ks = 0; ks < 4; ++ks) {
      const float4* p = (const float4*)&f_in[m15][ks * 32 + quad * 8];
      float4 a = p[0], b = p[1];
      float f[8] = {a.x, a.y, a.z, a.w, b.x, b.y, b.z, b.w};
      split8(f, fa_hi[ks], fa_lo[ks]);           // activations keep hi+lo
    }
    const float bf0 = b_f[(w * 2) * 16 + m15];       // hoisted off the tail
    const float bf1 = b_f[(w * 2 + 1) * 16 + m15];

    float cur[8], nxt[8];
#pragma unroll
    for (int j = 0; j < 8; ++j)                      // s=0 fragment (tt=0,ks=0)
      cur[j] = W_f[(size_t)(quad * 8 + j) * HIDD + (w * 2) * 16 + m15];

    f32x4 acc = {0.f, 0.f, 0.f, 0.f};
#pragma unroll
    for (int s = 0; s < 8; ++s) {
      const int tt = s >> 2, ks = s & 3;
      if (s < 7) {                                   // prefetch step s+1
        const int nt2 = (s + 1) >> 2, nk = (s + 1) & 3;
        const int hn  = (w * 2 + nt2) * 16 + m15;
#pragma unroll
        for (int j = 0; j < 8; ++j)
          nxt[j] = W_f[(size_t)(nk * 32 + quad * 8 + j) * HIDD + hn];
      }
      half8 bhi;
      cvt8(cur, bhi);                                // hi-only weight
      acc = MFMA(fa_hi[ks], bhi, acc);               // 2 MFMAs
      acc = MFMA(fa_lo[ks], bhi, acc);
      if (ks == 3) {
        const int   hc  = (w * 2 + tt) * 16 + m15;
        const float bfv = tt ? bf1 : bf0;
#pragma unroll
        for (int r = 0; r < 4; ++r)                  // D: row = batch, col = hc
          hidn[quad * 4 + r][hc] = fmaxf(acc[r] + bfv, 0.f);
        acc = (f32x4){0.f, 0.f, 0.f, 0.f};
      }
#pragma unroll
      for (int j = 0; j < 8; ++j) cur[j] = nxt[j];   // rotate (SSA-renamed)
    }
  }
  __syncthreads();

  // ================= stage 4: logits = hidden @ W_dec + b_dec ================
  // wave 0 only — FULL hi+lo precision kept (last layer feeds absmax directly)
  if (w == 0) {
    half8 ga_hi[4], ga_lo[4];
#pragma unroll
    for (int ks = 0; ks < 4; ++ks) {
      const float4* p = (const float4*)&hidn[m15][ks * 32 + quad * 8];
      float4 a = p[0], b = p[1];
      float f[8] = {a.x, a.y, a.z, a.w, b.x, b.y, b.z, b.w};
      split8(f, ga_hi[ks], ga_lo[ks]);
    }
    f32x4 acc = {0.f, 0.f, 0.f, 0.f};
#pragma unroll
    for (int ks = 0; ks < 4; ++ks) {
      float f[8];
#pragma unroll
      for (int j = 0; j < 8; ++j) {
        int k = ks * 32 + quad * 8 + j;
        f[j] = (m15 < OUTD) ? W_dec[(size_t)k * OUTD + m15] : 0.f;  // pad N 8->16
      }
      half8 bhi, blo;
      split8(f, bhi, blo);
      acc = MFMA(ga_hi[ks], bhi, acc);
      acc = MFMA(ga_lo[ks], bhi, acc);
      acc = MFMA(ga_hi[ks], blo, acc);
    }
    if (m15 < OUTD) {
      const float bd = b_dec[m15];
#pragma unroll
      for (int r = 0; r < 4; ++r) {
        const int m = quad * 4 + r;
        out[(size_t)(b0 + m) * OUTD + m15] = acc[r] + bd;
      }
    }
  }
}

extern "C" void kernel_launch(void* const* d_in, const int* in_sizes, int n_in,
                              void* d_out, int out_size, void* d_ws, size_t ws_size,
                              hipStream_t stream) {
  (void)in_sizes; (void)n_in; (void)d_ws; (void)ws_size; (void)out_size;
  const float* obs   = (const float*)d_in[0];
  const float* W_enc = (const float*)d_in[1];
  const float* b_enc = (const float*)d_in[2];
  const float* W_f   = (const float*)d_in[3];
  const float* b_f   = (const float*)d_in[4];
  const float* W_dec = (const float*)d_in[5];
  const float* b_dec = (const float*)d_in[6];
  float* out = (float*)d_out;

  dim3 grid(NB / BT);      // 2048 blocks
  dim3 block(THREADS);     // 256 threads = 4 waves
  gnn_fused<<<grid, block, 0, stream>>>(obs, W_enc, b_enc, W_f, b_f, W_dec, b_dec, out);
}

// Round 11
// 109.872 us; speedup vs baseline: 1.0958x; 1.0118x over previous
//
#include <hip/hip_runtime.h>
#include <stdint.h>

// Problem constants (fixed by the reference)
#define NB    32768   // batch
#define NS    16      // states per element
#define SS    32      // state size (K of stage 1)
#define ENCD  64      // encoder width
#define HIDD  128     // hidden width
#define OUTD  8       // output logits
#define BT    16      // batch elements per block
#define THREADS 256   // 4 waves

typedef _Float16 half8  __attribute__((ext_vector_type(8)));  // 8 f16 = 4 VGPRs
typedef __fp16   fp16x2 __attribute__((ext_vector_type(2)));  // cvt_pkrtz result type
typedef float    f32x4  __attribute__((ext_vector_type(4)));

#define MFMA(a, b, c) __builtin_amdgcn_mfma_f32_16x16x32_f16((a), (b), (c), 0, 0, 0)

// Split 8 floats into fp16 hi + lo: f = hi + lo + O(2^-20 |f|).
// Used for ACTIVATIONS (A-side) and the final layer only.
__device__ __forceinline__ void split8(const float* f, half8& hi, half8& lo) {
#pragma unroll
  for (int j = 0; j < 8; j += 2) {
    fp16x2 h  = __builtin_amdgcn_cvt_pkrtz(f[j], f[j + 1]);
    float  r0 = f[j]     - (float)h[0];
    float  r1 = f[j + 1] - (float)h[1];
    fp16x2 l2 = __builtin_amdgcn_cvt_pkrtz(r0, r1);
    hi[j] = (_Float16)(float)h[0];  hi[j + 1] = (_Float16)(float)h[1];
    lo[j] = (_Float16)(float)l2[0]; lo[j + 1] = (_Float16)(float)l2[1];
  }
}

// hi-only weight conversion (RTN casts, rel err 2^-12) — r10, kept.
__device__ __forceinline__ void cvt8(const float* f, half8& hi) {
#pragma unroll
  for (int j = 0; j < 8; ++j)
    hi[j] = (_Float16)f[j];
}

// R10 post-mortem: VALU volume cut bought ~0.5us -> volume not critical path.
// Residual is exposed latency in dependency chains. R11, ONE change: stage 3
// ran tt=0's 8-deep dependent MFMA chain fully before tt=1 (cur/nxt rotation
// forces it — compiler cannot interleave). Now BOTH tt fragment streams run
// simultaneously: two accumulators, MFMAs interleaved acc0/acc1, per-step
// W_f loads 8 -> 16 in flight. Per-chain math order unchanged -> absmax
// bit-identical (0.0009765625). Regs ~+20, inside the (256,4)=128 cap.
__global__ __launch_bounds__(THREADS, 4)
void gnn_fused(const float* __restrict__ obs,
               const float* __restrict__ W_enc,
               const float* __restrict__ b_enc,
               const float* __restrict__ W_f,
               const float* __restrict__ b_f,
               const float* __restrict__ W_dec,
               const float* __restrict__ b_dec,
               float* __restrict__ out)
{
  // stride 132 floats: rows 528 B (16B-aligned), row-to-row bank shift of 4
  __shared__ __align__(16) float f_in[BT][132];   // stage-2 output [batch][128]
  __shared__ __align__(16) float hidn[BT][132];   // stage-3 output [batch][128]

  const int tid  = threadIdx.x;
  const int w    = tid >> 6;     // wave 0..3
  const int l    = tid & 63;     // lane
  const int m15  = l & 15;
  const int quad = l >> 4;
  const int b0   = blockIdx.x * BT;

  // ---- stage-1 B-fragments: W_enc[k][e] columns, hi-only fp16 (16 VGPRs)
  half8 we_hi[4];
  float benc[4];
#pragma unroll
  for (int nt = 0; nt < 4; ++nt) {
    float f[8];
#pragma unroll
    for (int j = 0; j < 8; ++j)
      f[j] = W_enc[(size_t)(quad * 8 + j) * ENCD + nt * 16 + m15];
    cvt8(f, we_hi[nt]);
    benc[nt] = b_enc[nt * 16 + m15];
  }

  // ================= stage 1 (enc MFMA) + stage 2 (masked mean-pool) =========
  // wave handles batches [b0 + w*4, b0 + w*4 + 4), depth-1 rotating prefetch
  const float* bp = obs + (size_t)(b0 + w * 4) * (NS * SS) + m15 * SS + quad * 8;
  float4 c0 = ((const float4*)bp)[0];
  float4 c1 = ((const float4*)bp)[1];
#pragma unroll
  for (int i = 0; i < 4; ++i) {
    float4 n0, n1;
    if (i < 3) {  // prefetch next batch element
      const float* np = bp + (size_t)(i + 1) * (NS * SS);
      n0 = ((const float4*)np)[0];
      n1 = ((const float4*)np)[1];
    } else { n0 = c0; n1 = c1; }

    float f[8] = {c0.x, c0.y, c0.z, c0.w, c1.x, c1.y, c1.z, c1.w};

    // flags: lanes 0..15 hold states[b][n][0]; cumprod run length via ballot+ctz
    unsigned long long bal = __ballot((l < 16) && (f[0] == 1.0f));
    int run = __builtin_ctzll(~(bal >> 1));      // consecutive valid neighbors
    float inv = 1.0f / fmaxf((float)run, 1.0f);

    half8 ahi, alo;
    split8(f, ahi, alo);                         // A keeps hi+lo (exact-ish)

    const int bi = w * 4 + i;  // local batch row
#pragma unroll
    for (int nt = 0; nt < 4; ++nt) {
      f32x4 acc = {0.f, 0.f, 0.f, 0.f};
      acc = MFMA(ahi, we_hi[nt], acc);           // 2 MFMAs (B-lo dropped, r10)
      acc = MFMA(alo, we_hi[nt], acc);
      // D layout: lane holds enc[n = quad*4 + r][e = nt*16 + m15]
      float s = 0.f, e0 = 0.f;
#pragma unroll
      for (int r = 0; r < 4; ++r) {
        int n = quad * 4 + r;
        float v = fmaxf(acc[r] + benc[nt], 0.f);
        if (n == 0) e0 = v;                    // agent row
        if (n >= 1 && n <= run) s += v;        // valid neighbor
      }
      s += __shfl_xor(s, 16, 64);              // reduce across quads
      s += __shfl_xor(s, 32, 64);
      if (quad == 0) {
        f_in[bi][nt * 16 + m15]      = e0;      // agent_enc
        f_in[bi][64 + nt * 16 + m15] = s * inv; // agg
      }
    }
    c0 = n0; c1 = n1;
  }
  __syncthreads();

  // ================= stage 3: hidden = relu(f_in @ W_f + b_f) ================
  // single 16-row M-tile; wave w covers N-tiles 2w, 2w+1 — BOTH streams run
  // simultaneously: interleaved acc0/acc1 chains, 16 W_f loads in flight.
  {
    half8 fa_hi[4], fa_lo[4];
#pragma unroll
    for (int ks = 0; ks < 4; ++ks) {
      const float4* p = (const float4*)&f_in[m15][ks * 32 + quad * 8];
      float4 a = p[0], b = p[1];
      float f[8] = {a.x, a.y, a.z, a.w, b.x, b.y, b.z, b.w};
      split8(f, fa_hi[ks], fa_lo[ks]);           // activations keep hi+lo
    }
    const int   h0  = (w * 2) * 16 + m15;        // tt=0 column
    const int   h1  = (w * 2 + 1) * 16 + m15;    // tt=1 column
    const float bf0 = b_f[h0];
    const float bf1 = b_f[h1];

    float cur0[8], cur1[8], nxt0[8], nxt1[8];
#pragma unroll
    for (int j = 0; j < 8; ++j) {                // ks=0 fragments, both streams
      cur0[j] = W_f[(size_t)(quad * 8 + j) * HIDD + h0];
      cur1[j] = W_f[(size_t)(quad * 8 + j) * HIDD + h1];
    }

    f32x4 acc0 = {0.f, 0.f, 0.f, 0.f};
    f32x4 acc1 = {0.f, 0.f, 0.f, 0.f};
#pragma unroll
    for (int ks = 0; ks < 4; ++ks) {
      if (ks < 3) {                              // prefetch ks+1, both streams
#pragma unroll
        for (int j = 0; j < 8; ++j) {
          const size_t row = (size_t)((ks + 1) * 32 + quad * 8 + j) * HIDD;
          nxt0[j] = W_f[row + h0];
          nxt1[j] = W_f[row + h1];
        }
      }
      half8 b0h, b1h;
      cvt8(cur0, b0h);
      cvt8(cur1, b1h);
      acc0 = MFMA(fa_hi[ks], b0h, acc0);         // chains interleaved:
      acc1 = MFMA(fa_hi[ks], b1h, acc1);         // acc0/acc1 alternate, each
      acc0 = MFMA(fa_lo[ks], b0h, acc0);         // chain's internal order is
      acc1 = MFMA(fa_lo[ks], b1h, acc1);         // unchanged (same numerics)
#pragma unroll
      for (int j = 0; j < 8; ++j) { cur0[j] = nxt0[j]; cur1[j] = nxt1[j]; }
    }
#pragma unroll
    for (int r = 0; r < 4; ++r) {                // D: row = batch, col = h
      hidn[quad * 4 + r][h0] = fmaxf(acc0[r] + bf0, 0.f);
      hidn[quad * 4 + r][h1] = fmaxf(acc1[r] + bf1, 0.f);
    }
  }
  __syncthreads();

  // ================= stage 4: logits = hidden @ W_dec + b_dec ================
  // wave 0 only — FULL hi+lo precision kept (last layer feeds absmax directly)
  if (w == 0) {
    half8 ga_hi[4], ga_lo[4];
#pragma unroll
    for (int ks = 0; ks < 4; ++ks) {
      const float4* p = (const float4*)&hidn[m15][ks * 32 + quad * 8];
      float4 a = p[0], b = p[1];
      float f[8] = {a.x, a.y, a.z, a.w, b.x, b.y, b.z, b.w};
      split8(f, ga_hi[ks], ga_lo[ks]);
    }
    f32x4 acc = {0.f, 0.f, 0.f, 0.f};
#pragma unroll
    for (int ks = 0; ks < 4; ++ks) {
      float f[8];
#pragma unroll
      for (int j = 0; j < 8; ++j) {
        int k = ks * 32 + quad * 8 + j;
        f[j] = (m15 < OUTD) ? W_dec[(size_t)k * OUTD + m15] : 0.f;  // pad N 8->16
      }
      half8 bhi, blo;
      split8(f, bhi, blo);
      acc = MFMA(ga_hi[ks], bhi, acc);
      acc = MFMA(ga_lo[ks], bhi, acc);
      acc = MFMA(ga_hi[ks], blo, acc);
    }
    if (m15 < OUTD) {
      const float bd = b_dec[m15];
#pragma unroll
      for (int r = 0; r < 4; ++r) {
        const int m = quad * 4 + r;
        out[(size_t)(b0 + m) * OUTD + m15] = acc[r] + bd;
      }
    }
  }
}

extern "C" void kernel_launch(void* const* d_in, const int* in_sizes, int n_in,
                              void* d_out, int out_size, void* d_ws, size_t ws_size,
                              hipStream_t stream) {
  (void)in_sizes; (void)n_in; (void)d_ws; (void)ws_size; (void)out_size;
  const float* obs   = (const float*)d_in[0];
  const float* W_enc = (const float*)d_in[1];
  const float* b_enc = (const float*)d_in[2];
  const float* W_f   = (const float*)d_in[3];
  const float* b_f   = (const float*)d_in[4];
  const float* W_dec = (const float*)d_in[5];
  const float* b_dec = (const float*)d_in[6];
  float* out = (float*)d_out;

  dim3 grid(NB / BT);      // 2048 blocks
  dim3 block(THREADS);     // 256 threads = 4 waves
  gnn_fused<<<grid, block, 0, stream>>>(obs, W_enc, b_enc, W_f, b_f, W_dec, b_dec, out);
}